// Round 6
// baseline (46.335 us; speedup 1.0000x reference)
//
#include <hip/hip_runtime.h>

// TruncatedLIF: depth-8 truncated linear recurrence along T.
// inputs (B,T,D) f32, params rou/a/b (D,) f32, out (B,T,D) f32.
// out[t,d] = sum_{k=0..8} drive[t-k,d] * prod_{j=t-k+1..t} prefix[j,d]
//   prefix = rou*(1 - b*x), drive = (1-rou)*a*x
// Memory-bound. R6: float4/lane (16B transactions, matching the 6.29 TB/s
// copy ubench) + sched_barrier(0) to pin the 8-load cluster (R5's cluster
// was re-interleaved by the scheduler: VGPR=36 proved it). TC=128, nt
// stores. grid=256 blocks x 256 thr = 1 block/CU, 4 waves/CU.

#define B_ 8
#define T_ 4096
#define D_ 1024
#define TRUNC_ 8
#define TC 128                // time-chunk per block
#define NCHUNK (T_ / TC)      // 32 chunks
#define D4 (D_ / 4)           // 256 float4 groups per row

typedef float vf4 __attribute__((ext_vector_type(4)));

__global__ __launch_bounds__(256) void lif_kernel(
    const float* __restrict__ x,
    const float* __restrict__ rou,
    const float* __restrict__ a,
    const float* __restrict__ bparm,
    float* __restrict__ out)
{
    const int tid   = threadIdx.x;              // 0..255 -> channels 4*tid..4*tid+3
    const int chunk = blockIdx.x % NCHUNK;
    const int batch = blockIdx.x / NCHUNK;
    const int t0    = chunk * TC;
    const int tw    = (t0 >= TRUNC_) ? (t0 - TRUNC_) : 0;
    const int tend  = t0 + TC;

    const vf4 rv = reinterpret_cast<const vf4*>(rou)[tid];
    const vf4 av = reinterpret_cast<const vf4*>(a)[tid];
    const vf4 bv = reinterpret_cast<const vf4*>(bparm)[tid];

    float rr[4] = {rv.x, rv.y, rv.z, rv.w};
    float bc[4] = {bv.x, bv.y, bv.z, bv.w};
    // c = (1-rou)*a  (same association as reference's (1.0-r_)*a_*seq)
    float cc[4] = {(1.0f - rv.x) * av.x,
                   (1.0f - rv.y) * av.y,
                   (1.0f - rv.z) * av.z,
                   (1.0f - rv.w) * av.w};

    // 9-deep sliding window per channel; fully unrolled -> stays in VGPRs.
    float r[4][9];
#pragma unroll
    for (int ch = 0; ch < 4; ++ch)
#pragma unroll
        for (int k = 0; k < 9; ++k) r[ch][k] = 0.0f;

    const vf4* __restrict__ xin =
        reinterpret_cast<const vf4*>(x) + (size_t)batch * T_ * D4;
    vf4* __restrict__ op =
        reinterpret_cast<vf4*>(out) + (size_t)batch * T_ * D4;

    // One recurrence step for one loaded float4; returns output float4.
    auto step = [&](const vf4 xv) -> vf4 {
        float xs[4] = {xv.x, xv.y, xv.z, xv.w};
        float os[4];
#pragma unroll
        for (int ch = 0; ch < 4; ++ch) {
            const float p  = rr[ch] * (1.0f - bc[ch] * xs[ch]);
            const float dr = cc[ch] * xs[ch];
#pragma unroll
            for (int k = 8; k >= 1; --k) r[ch][k] = r[ch][k - 1] * p;
            r[ch][0] = dr;
            float s = dr;
#pragma unroll
            for (int k = 1; k <= 8; ++k) s += r[ch][k];  // reference's add order
            os[ch] = s;
        }
        vf4 o; o.x = os[0]; o.y = os[1]; o.z = os[2]; o.w = os[3];
        return o;
    };

    // Halo warm-up: build window state, no stores (0 iters for chunk 0).
    for (int t = tw; t < t0; ++t) {
        (void)step(xin[(size_t)t * D4 + tid]);
    }

    // Main loop: 8-step unroll. Loads clustered, then a scheduling fence so
    // the compiler cannot sink them into the compute (128 B/lane in flight).
    for (int t = t0; t < tend; t += 8) {
        const size_t i0 = (size_t)t * D4 + tid;
        vf4 xv[8];
#pragma unroll
        for (int u = 0; u < 8; ++u) xv[u] = xin[i0 + (size_t)u * D4];
        __builtin_amdgcn_sched_barrier(0);   // keep all 8 loads issued first
        vf4 ov[8];
#pragma unroll
        for (int u = 0; u < 8; ++u) ov[u] = step(xv[u]);
#pragma unroll
        for (int u = 0; u < 8; ++u)
            __builtin_nontemporal_store(ov[u], &op[i0 + (size_t)u * D4]);
    }
}

extern "C" void kernel_launch(void* const* d_in, const int* in_sizes, int n_in,
                              void* d_out, int out_size, void* d_ws, size_t ws_size,
                              hipStream_t stream) {
    const float* x    = (const float*)d_in[0];
    const float* rou  = (const float*)d_in[1];
    const float* a    = (const float*)d_in[2];
    const float* bprm = (const float*)d_in[3];
    float* out        = (float*)d_out;
    // truncation_steps (d_in[4]) is fixed at 8; hardcoded as TRUNC_.

    dim3 grid(B_ * NCHUNK);   // 256 blocks = 1 per CU
    dim3 block(256);          // 4 waves/block
    lif_kernel<<<grid, block, 0, stream>>>(x, rou, a, bprm, out);
}

// Round 7
// 45.596 us; speedup vs baseline: 1.0162x; 1.0162x over previous
//
#include <hip/hip_runtime.h>

// TruncatedLIF: depth-8 truncated linear recurrence along T.
// inputs (B,T,D) f32, params rou/a/b (D,) f32, out (B,T,D) f32.
// out[t,d] = sum_{k=0..8} drive[t-k,d] * prod_{j=t-k+1..t} prefix[j,d]
//   prefix = rou*(1 - b*x), drive = (1-rou)*a*x
// Memory-bound. R7: R5 config (float2/lane, unroll 8, TC=128, nt stores)
// + D-split 2 -> 512 blocks x 256 thr = 2 blocks/CU so halo-warmup/tail
// bubbles of co-resident blocks stagger (R4-R6 had 1 synchronized
// block/CU). Same traffic, same halo bytes.

#define B_ 8
#define T_ 4096
#define D_ 1024
#define TRUNC_ 8
#define TC 128                // time-chunk per block
#define NCHUNK (T_ / TC)      // 32 chunks
#define D2 (D_ / 2)           // 512 float2 groups per row
#define DSPLIT 2              // blocks per (batch,chunk) along D
#define D2B (D2 / DSPLIT)     // 256 float2 groups per block

typedef float vf2 __attribute__((ext_vector_type(2)));

__global__ __launch_bounds__(256) void lif_kernel(
    const float* __restrict__ x,
    const float* __restrict__ rou,
    const float* __restrict__ a,
    const float* __restrict__ bparm,
    float* __restrict__ out)
{
    const int tid    = threadIdx.x;             // 0..255
    const int dhalf  = blockIdx.x & (DSPLIT - 1);
    const int bc_    = blockIdx.x / DSPLIT;     // (batch,chunk) id, 0..255
    const int chunk  = bc_ % NCHUNK;
    const int batch  = bc_ / NCHUNK;
    const int gd     = dhalf * D2B + tid;       // float2-group index in row
    const int t0     = chunk * TC;
    const int tw     = (t0 >= TRUNC_) ? (t0 - TRUNC_) : 0;
    const int tend   = t0 + TC;

    const vf2 rv = reinterpret_cast<const vf2*>(rou)[gd];
    const vf2 av = reinterpret_cast<const vf2*>(a)[gd];
    const vf2 bv = reinterpret_cast<const vf2*>(bparm)[gd];

    float rr[2] = {rv.x, rv.y};
    float bc[2] = {bv.x, bv.y};
    // c = (1-rou)*a  (same association as reference's (1.0-r_)*a_*seq)
    float cc[2] = {(1.0f - rv.x) * av.x,
                   (1.0f - rv.y) * av.y};

    // 9-deep sliding window per channel; fully unrolled -> stays in VGPRs.
    float r[2][9];
#pragma unroll
    for (int ch = 0; ch < 2; ++ch)
#pragma unroll
        for (int k = 0; k < 9; ++k) r[ch][k] = 0.0f;

    const vf2* __restrict__ xin =
        reinterpret_cast<const vf2*>(x) + (size_t)batch * T_ * D2;
    vf2* __restrict__ op =
        reinterpret_cast<vf2*>(out) + (size_t)batch * T_ * D2;

    // One recurrence step for one loaded float2; returns output float2.
    auto step = [&](const vf2 xv) -> vf2 {
        float xs[2] = {xv.x, xv.y};
        float os[2];
#pragma unroll
        for (int ch = 0; ch < 2; ++ch) {
            const float p  = rr[ch] * (1.0f - bc[ch] * xs[ch]);
            const float dr = cc[ch] * xs[ch];
#pragma unroll
            for (int k = 8; k >= 1; --k) r[ch][k] = r[ch][k - 1] * p;
            r[ch][0] = dr;
            float s = dr;
#pragma unroll
            for (int k = 1; k <= 8; ++k) s += r[ch][k];  // reference's add order
            os[ch] = s;
        }
        vf2 o; o.x = os[0]; o.y = os[1];
        return o;
    };

    // Halo warm-up: build window state, no stores (0 iters for chunk 0).
    for (int t = tw; t < t0; ++t) {
        (void)step(xin[(size_t)t * D2 + gd]);
    }

    // Main loop: 8-step unroll, loads clustered first; streaming stores.
    for (int t = t0; t < tend; t += 8) {
        const size_t i0 = (size_t)t * D2 + gd;
        vf2 x0 = xin[i0];
        vf2 x1 = xin[i0 + 1 * D2];
        vf2 x2 = xin[i0 + 2 * D2];
        vf2 x3 = xin[i0 + 3 * D2];
        vf2 x4 = xin[i0 + 4 * D2];
        vf2 x5 = xin[i0 + 5 * D2];
        vf2 x6 = xin[i0 + 6 * D2];
        vf2 x7 = xin[i0 + 7 * D2];
        vf2 o0 = step(x0);
        vf2 o1 = step(x1);
        vf2 o2 = step(x2);
        vf2 o3 = step(x3);
        vf2 o4 = step(x4);
        vf2 o5 = step(x5);
        vf2 o6 = step(x6);
        vf2 o7 = step(x7);
        __builtin_nontemporal_store(o0, &op[i0]);
        __builtin_nontemporal_store(o1, &op[i0 + 1 * D2]);
        __builtin_nontemporal_store(o2, &op[i0 + 2 * D2]);
        __builtin_nontemporal_store(o3, &op[i0 + 3 * D2]);
        __builtin_nontemporal_store(o4, &op[i0 + 4 * D2]);
        __builtin_nontemporal_store(o5, &op[i0 + 5 * D2]);
        __builtin_nontemporal_store(o6, &op[i0 + 6 * D2]);
        __builtin_nontemporal_store(o7, &op[i0 + 7 * D2]);
    }
}

extern "C" void kernel_launch(void* const* d_in, const int* in_sizes, int n_in,
                              void* d_out, int out_size, void* d_ws, size_t ws_size,
                              hipStream_t stream) {
    const float* x    = (const float*)d_in[0];
    const float* rou  = (const float*)d_in[1];
    const float* a    = (const float*)d_in[2];
    const float* bprm = (const float*)d_in[3];
    float* out        = (float*)d_out;
    // truncation_steps (d_in[4]) is fixed at 8; hardcoded as TRUNC_.

    dim3 grid(B_ * NCHUNK * DSPLIT);  // 512 blocks = 2 per CU
    dim3 block(256);                  // 4 waves/block
    lif_kernel<<<grid, block, 0, stream>>>(x, rou, a, bprm, out);
}